// Round 9
// baseline (126.254 us; speedup 1.0000x reference)
//
#include <hip/hip_runtime.h>
#include <hip/hip_bf16.h>
#include <stdint.h>

#define BTOT 4096
#define RR   64
#define DIMD 128
#define WROW 40   /* wave-buffer row stride in shorts (80 B): bank-friendly */

typedef short s16x8 __attribute__((ext_vector_type(8)));
typedef float f32x4 __attribute__((ext_vector_type(4)));

__device__ __forceinline__ unsigned short f2bf(float x) {
  __hip_bfloat16 h = __float2bfloat16(x);
  return __builtin_bit_cast(unsigned short, h);
}
__device__ __forceinline__ float bf2f(unsigned short u) {
  unsigned int v = ((unsigned int)u) << 16;
  return __builtin_bit_cast(float, v);
}

// ---------------------------------------------------------------------------
// Pre-kernel: qproj[b,k] = sum_d query_r[b,d]*W1[k,128+d] + b1[k]  (fp32),
// offset_emb passthrough, and blocks 0/1 emit XOR-swizzled bf16 copies of
// W1a / W2 into ws.  Swizzle: element (k,d) at k*128 + (d ^ ((k&7)<<3)).
// ---------------------------------------------------------------------------
__global__ __launch_bounds__(256) void prep_kernel(
    const float* __restrict__ W1, const float* __restrict__ b1,
    const float* __restrict__ query_r, const float* __restrict__ W2,
    const float* __restrict__ offset_emb,
    float* __restrict__ qproj, unsigned short* __restrict__ w1a_swz,
    unsigned short* __restrict__ w2_swz, float* __restrict__ out)
{
  __shared__ float w1b[128 * 132];   // +4 pad
  __shared__ float qrs[256];
  const int tid = threadIdx.x;

  { // offset_emb passthrough (1 float4 per thread; 512 blocks cover 4096x128)
    const size_t ob = (size_t)blockIdx.x * 8 * DIMD + (size_t)tid * 4;
    *reinterpret_cast<float4*>(out + (size_t)BTOT * DIMD + ob) =
        *reinterpret_cast<const float4*>(offset_emb + ob);
  }
  { // stage W1b fp32 into padded LDS
    const int k = tid >> 1, d0 = (tid & 1) * 64;
    const float* src = W1 + k * 256 + 128 + d0;
    float* dst = &w1b[k * 132 + d0];
    #pragma unroll
    for (int i = 0; i < 64; i += 4)
      *reinterpret_cast<float4*>(dst + i) = *reinterpret_cast<const float4*>(src + i);
  }
  if (blockIdx.x < 2) { // swizzled bf16 weights
    const float* Wsrc = (blockIdx.x == 0) ? W1 : W2;
    unsigned short* dstw = (blockIdx.x == 0) ? w1a_swz : w2_swz;
    const int stride = (blockIdx.x == 0) ? 256 : 128;
    for (int i = tid; i < 128 * 128; i += 256) {
      const int k = i >> 7, d = i & 127;
      dstw[k * 128 + (d ^ ((k & 7) << 3))] = f2bf(Wsrc[k * stride + d]);
    }
  }
  __syncthreads();

  const int b0 = blockIdx.x * 8;
  const int k = tid & 127, bh = tid >> 7;
  for (int p = 0; p < 4; ++p) {
    const int b = b0 + p * 2;
    qrs[tid] = query_r[(size_t)(b + bh) * DIMD + k];
    __syncthreads();
    float acc = b1[k];
    const float* qq = &qrs[bh * 128];
    const float* wr = &w1b[k * 132];
    #pragma unroll
    for (int d = 0; d < 128; d += 4) {
      float4 wv = *reinterpret_cast<const float4*>(wr + d);
      float4 qv = *reinterpret_cast<const float4*>(qq + d);
      acc = fmaf(wv.x, qv.x, acc); acc = fmaf(wv.y, qv.y, acc);
      acc = fmaf(wv.z, qv.z, acc); acc = fmaf(wv.w, qv.w, acc);
    }
    qproj[(size_t)(b + bh) * DIMD + k] = acc;
    __syncthreads();
  }
}

// ---------------------------------------------------------------------------
// Main kernel: 512 blocks x 512 threads (8 waves), each wave owns ONE b.
// Contraction in four 32-wide quarters through a 1.25 KB per-wave buffer
// (R8 body, proven 96 VGPR / zero spill). CHANGE vs R8: W2 is NOT staged in
// LDS -- GEMM2 B-fragments are read straight from the swizzled global table
// (32 KB, shared chip-wide -> L1/L2-resident; ~1.7 TB/s aggregate demand vs
// 34 TB/s L2). LDS = 32 KB (W1a) + 8 x 1.25 KB = 42 KB: under the observed
// gfx950 co-residency boundary (74/80 KB blocks never co-scheduled, 16 KB
// did) -> 2 blocks/CU = 16 waves/CU. Bare __launch_bounds__(512) = the only
// codegen config across R2-R8 that never spilled. Per-quarter asm "memory"
// fences bound W2-load hoisting to <=1 quarter (8 loads, 32 VGPR transient).
// Zero barriers in the loop; all DS traffic wave-private (in-order DS pipe).
// ---------------------------------------------------------------------------
__global__ __launch_bounds__(512) void main_kernel(
    const float* __restrict__ query_emb,
    const float* __restrict__ refer_embs, const float* __restrict__ refer_r,
    const float* __restrict__ start_embs, const float* __restrict__ b2,
    const float* __restrict__ qproj, const unsigned short* __restrict__ w1a_swz,
    const unsigned short* __restrict__ w2_swz, float* __restrict__ out)
{
  __shared__ unsigned short lds_w1a[128 * 128];   // 32 KB, swizzled
  __shared__ unsigned short wbuf[8][16 * WROW];   // 1.25 KB per wave

  const int tid  = threadIdx.x;
  const int wave = tid >> 6;
  const int lane = tid & 63;
  const int g    = lane >> 4;   // k-group
  const int c    = lane & 15;   // row/col-in-tile

  { // stage swizzled W1a (linear uint4 copy; swizzle pre-applied in ws)
    const uint4* s1 = reinterpret_cast<const uint4*>(w1a_swz);
    uint4* d1 = reinterpret_cast<uint4*>(lds_w1a);
    #pragma unroll
    for (int i = 0; i < 4; ++i)
      d1[tid + 512 * i] = s1[tid + 512 * i];
  }
  __syncthreads();   // the ONLY barrier

  unsigned short* mybuf = &wbuf[wave][0];
  const int srl = lane >> 2;           // staging local row 0..15
  const int q   = lane & 3;            // staging quarter-of-row (8 floats)
  const int swc = (c & 7) << 3;        // weight swizzle for row nt*16+c
  const int rl4 = 4 * g;

  const int b = blockIdx.x * 8 + wave;  // this wave's b

  float qn[8], b2v[8], acc[8];
  #pragma unroll
  for (int nt = 0; nt < 8; ++nt) {
    qn[nt]  = qproj[(size_t)b * DIMD + nt * 16 + c];
    b2v[nt] = b2[nt * 16 + c];
    acc[nt] = 0.f;
  }

  for (int it = 0; it < 4; ++it) {
    const size_t rowbase = ((size_t)b * RR + it * 16 + srl) * DIMD;
    uint4 bp[4];          // packed bias (row layout), one per quarter
    f32x4 Ch[8];
    #pragma unroll
    for (int nt = 0; nt < 8; ++nt) Ch[nt] = (f32x4){qn[nt], qn[nt], qn[nt], qn[nt]};

    // ================= GEMM1 (four 32-wide d-quarters) =================
    #pragma unroll
    for (int Q = 0; Q < 4; ++Q) {
      const size_t gb = rowbase + Q * 32 + q * 8;
      const float4 rv0 = *reinterpret_cast<const float4*>(refer_r    + gb);
      const float4 rv1 = *reinterpret_cast<const float4*>(refer_r    + gb + 4);
      const float4 ev0 = *reinterpret_cast<const float4*>(refer_embs + gb);
      const float4 ev1 = *reinterpret_cast<const float4*>(refer_embs + gb + 4);
      const float4 sv0 = *reinterpret_cast<const float4*>(start_embs + gb);
      const float4 sv1 = *reinterpret_cast<const float4*>(start_embs + gb + 4);
      { // stage refer_r quarter (one uint4 per lane)
        union { unsigned short u[8]; uint4 v; } pk;
        pk.u[0] = f2bf(rv0.x); pk.u[1] = f2bf(rv0.y);
        pk.u[2] = f2bf(rv0.z); pk.u[3] = f2bf(rv0.w);
        pk.u[4] = f2bf(rv1.x); pk.u[5] = f2bf(rv1.y);
        pk.u[6] = f2bf(rv1.z); pk.u[7] = f2bf(rv1.w);
        *reinterpret_cast<uint4*>(&mybuf[srl * WROW + q * 8]) = pk.v;
      }
      { // bias quarter = ev - sv - rv, packed bf16 (row layout, in regs)
        union { unsigned short u[8]; uint4 v; } pk;
        pk.u[0] = f2bf(ev0.x - sv0.x - rv0.x); pk.u[1] = f2bf(ev0.y - sv0.y - rv0.y);
        pk.u[2] = f2bf(ev0.z - sv0.z - rv0.z); pk.u[3] = f2bf(ev0.w - sv0.w - rv0.w);
        pk.u[4] = f2bf(ev1.x - sv1.x - rv1.x); pk.u[5] = f2bf(ev1.y - sv1.y - rv1.y);
        pk.u[6] = f2bf(ev1.z - sv1.z - rv1.z); pk.u[7] = f2bf(ev1.w - sv1.w - rv1.w);
        bp[Q] = pk.v;
      }
      asm volatile("s_waitcnt lgkmcnt(0)" ::: "memory");
      const s16x8 af = *reinterpret_cast<const s16x8*>(&mybuf[c * WROW + g * 8]);
      #pragma unroll
      for (int nt = 0; nt < 8; ++nt) {
        s16x8 wf = *reinterpret_cast<const s16x8*>(
            &lds_w1a[(nt * 16 + c) * DIMD + ((Q * 32 + g * 8) ^ swc)]);
        Ch[nt] = __builtin_amdgcn_mfma_f32_16x16x32_bf16(af, wf, Ch[nt], 0, 0, 0);
      }
      asm volatile("s_waitcnt lgkmcnt(0)" ::: "memory");  // af read done before restage
    }

    // ================= GEMM2 (four 32-wide k_hid-quarters) =================
    f32x4 Ca[8];
    #pragma unroll
    for (int nt = 0; nt < 8; ++nt) Ca[nt] = (f32x4){b2v[nt], b2v[nt], b2v[nt], b2v[nt]};
    #pragma unroll
    for (int Q = 0; Q < 4; ++Q) {
      // h quarter (relu, bf16) at C positions: cols 2Q..2Q+1 of the nt grid
      #pragma unroll
      for (int ntl = 0; ntl < 2; ++ntl)
        #pragma unroll
        for (int r = 0; r < 4; ++r)
          mybuf[(rl4 + r) * WROW + ntl * 16 + c] = f2bf(fmaxf(Ch[2 * Q + ntl][r], 0.f));
      asm volatile("s_waitcnt lgkmcnt(0)" ::: "memory");
      const s16x8 hf = *reinterpret_cast<const s16x8*>(&mybuf[c * WROW + g * 8]);
      #pragma unroll
      for (int nt = 0; nt < 8; ++nt) {
        // W2 B-fragment from GLOBAL (L1/L2-resident 32 KB table)
        s16x8 wf = *reinterpret_cast<const s16x8*>(
            &w2_swz[(nt * 16 + c) * DIMD + ((Q * 32 + g * 8) ^ swc)]);
        Ca[nt] = __builtin_amdgcn_mfma_f32_16x16x32_bf16(hf, wf, Ca[nt], 0, 0, 0);
      }
      asm volatile("s_waitcnt lgkmcnt(0)" ::: "memory");  // hf read done before restage
    }

    // ================= bias dot + reduce (four quarters) =================
    #pragma unroll
    for (int Q = 0; Q < 4; ++Q) {
      *reinterpret_cast<uint4*>(&mybuf[srl * WROW + q * 8]) = bp[Q];
      asm volatile("s_waitcnt lgkmcnt(0)" ::: "memory");
      #pragma unroll
      for (int ntl = 0; ntl < 2; ++ntl) {
        const int nt = 2 * Q + ntl;
        float s = 0.f;
        #pragma unroll
        for (int r = 0; r < 4; ++r) {
          const float bcv = bf2f(mybuf[(rl4 + r) * WROW + ntl * 16 + c]);
          s = fmaf(Ca[nt][r], bcv, s);
        }
        s += __shfl_xor(s, 16);
        s += __shfl_xor(s, 32);
        acc[nt] += s;
      }
      asm volatile("s_waitcnt lgkmcnt(0)" ::: "memory");  // reads done before restage
    }
  }

  // ---- epilogue
  if (lane < 16) {
    #pragma unroll
    for (int nt = 0; nt < 8; ++nt)
      out[(size_t)b * DIMD + nt * 16 + c] =
          query_emb[(size_t)b * DIMD + nt * 16 + c] + acc[nt];
  }
}

extern "C" void kernel_launch(void* const* d_in, const int* in_sizes, int n_in,
                              void* d_out, int out_size, void* d_ws, size_t ws_size,
                              hipStream_t stream) {
  const float* query_emb  = (const float*)d_in[0];
  const float* offset_emb = (const float*)d_in[1];
  const float* refer_embs = (const float*)d_in[2];
  const float* query_r    = (const float*)d_in[3];
  const float* refer_r    = (const float*)d_in[4];
  const float* start_embs = (const float*)d_in[5];
  const float* W1 = (const float*)d_in[6];
  const float* b1 = (const float*)d_in[7];
  const float* W2 = (const float*)d_in[8];
  const float* b2 = (const float*)d_in[9];
  float* out = (float*)d_out;

  float* qproj = (float*)d_ws;                       // 4096*128 f32 = 2 MB
  unsigned short* w1a_swz =
      (unsigned short*)((char*)d_ws + (size_t)BTOT * DIMD * sizeof(float));
  unsigned short* w2_swz = w1a_swz + 128 * 128;      // +32 KB each

  hipLaunchKernelGGL(prep_kernel, dim3(512), dim3(256), 0, stream,
                     W1, b1, query_r, W2, offset_emb, qproj, w1a_swz, w2_swz, out);
  hipLaunchKernelGGL(main_kernel, dim3(512), dim3(512), 0, stream,
                     query_emb, refer_embs, refer_r, start_embs,
                     b2, qproj, w1a_swz, w2_swz, out);
}